// Round 6
// baseline (178.225 us; speedup 1.0000x reference)
//
#include <hip/hip_runtime.h>
#include <cstdint>
#include <cstddef>

typedef unsigned short u16;
typedef u16   u16x8  __attribute__((ext_vector_type(8)));
typedef u16   u16x4  __attribute__((ext_vector_type(4)));
typedef __bf16 bf16x8 __attribute__((ext_vector_type(8)));
typedef float f32x4  __attribute__((ext_vector_type(4)));
typedef float f32x2  __attribute__((ext_vector_type(2)));

__device__ __forceinline__ u16 f2bf(float f) {
  unsigned int x = __builtin_bit_cast(unsigned int, f);
  x += 0x7fffu + ((x >> 16) & 1u);   // RNE
  return (u16)(x >> 16);
}

// ---------------------------------------------------------------------------
// Fragment-subtile layout, K-MAJOR ordering (R5 post-mortem: rt-major gave
// 32KB-strided frag streams -> L1 set aliasing, no contiguity).
// Matrix [R rows][1024 k] bf16 stored as 1KB subtiles; subtile (rt,k32) at
// u16 offset (k32*NRT + rt)*512, NRT = R/16 (A: 512, B: 64). Inside a
// subtile, lane l = (kq = (k>>3)&3)*16 + (r&15) owns the 16B chunk
// k = k32*32+kq*8..+7 -- exactly the mfma_16x16x32 A/B operand mapping.
// A GEMM iteration's 4 frags are one contiguous 4KB block.
// ---------------------------------------------------------------------------

// ---------------------------------------------------------------------------
// Kernel 1: blocks 0..255   -> transpose W21/W22 -> Wt in frag layout
//           blocks 256..767 -> h1 = relu(x@W1+b1), one 16-row tile per block,
//                              verified FMA chains, staged through LDS
//                              (XOR-chunk swizzle) and stored frag-coalesced.
//                              Also zeroes head rows (ws poisoned).
// Identical math to R4/R5 (verified, absmax 0.015625); only the subtile
// offset arithmetic changed to K-major.
// ---------------------------------------------------------------------------
__global__ __launch_bounds__(256) void k_prep(const float* __restrict__ W21,
                                              const float* __restrict__ W22,
                                              u16* __restrict__ Wtf,
                                              const float* __restrict__ x,
                                              const float* __restrict__ W1,
                                              const float* __restrict__ b1,
                                              u16* __restrict__ h1f,
                                              float* __restrict__ head) {
  __shared__ u16 smem[16 * 1024];          // 32 KB (transpose path aliases 64x65)
  const int b  = blockIdx.x;
  const int t  = threadIdx.x;
  const int l  = t & 63, wv = t >> 6;
  const int lrow = l & 15, kq = l >> 4;

  if (b < 256) {
    // ---- W21/W22 transpose -> Wt frag layout (NRT_B = 64) ----
    u16 (*s)[65] = (u16(*)[65])smem;       // s[k-local][n-local]
    const int mat = b >> 7;
    const int tt  = b & 127;
    const int k0  = (tt >> 3) * 64;        // 16 k-panels of 64
    const int n0  = (tt & 7) * 64;         // 8 n-panels of 64
    const float* W = mat ? W22 : W21;
    const int tx = t & 63;
    const int ty = t >> 6;
#pragma unroll
    for (int i = 0; i < 16; ++i) {
      int r = i * 4 + ty;
      s[r][tx] = f2bf(W[(size_t)(k0 + r) * 512 + n0 + tx]);
    }
    __syncthreads();
    // 8 subtiles in this 64n x 64k region: wave wv owns ntile wv, both k32l.
    const int ntg0  = (mat * 512 + n0) >> 4;   // + wv
    const int k32g0 = k0 >> 5;                 // + k32l
#pragma unroll
    for (int k32l = 0; k32l < 2; ++k32l) {
      u16x8 v;
#pragma unroll
      for (int e = 0; e < 8; ++e)
        v[e] = s[k32l * 32 + kq * 8 + e][wv * 16 + lrow];
      *(u16x8*)(Wtf + (size_t)((k32g0 + k32l) * 64 + ntg0 + wv) * 512 + l * 8) = v;
    }
  } else {
    // ---- h1 tile (16 rows) -> frag layout (NRT_A = 512) ----
    const int mt    = b - 256;               // 0..511
    const int row0t = mt * 16;
    if (t < 16)
      *(f32x4*)(head + 4 * (size_t)(row0t + t)) = f32x4{0.f, 0.f, 0.f, 0.f};
    const int c4 = t * 4;                    // thread owns cols 4t..4t+3
    f32x4 bv = *(const f32x4*)(b1 + c4);
    for (int g = 0; g < 2; ++g) {
      const int row0 = row0t + g * 8;
      f32x4 acc[8];
#pragma unroll
      for (int r = 0; r < 8; ++r) acc[r] = bv;
#pragma unroll
      for (int f = 0; f < 8; ++f) {
        f32x4 wvv = *(const f32x4*)(W1 + f * 1024 + c4);
#pragma unroll
        for (int r = 0; r < 8; ++r) {
          float xv = x[(size_t)(row0 + r) * 8 + f];   // block-uniform -> s_load
#pragma unroll
          for (int e = 0; e < 4; ++e) acc[r][e] = fmaf(xv, wvv[e], acc[r][e]);
        }
      }
      // store to LDS, chunk-swizzled: chunk c' = c ^ (row&7), 16B units intact
#pragma unroll
      for (int rr = 0; rr < 8; ++rr) {
        u16x4 o;
#pragma unroll
        for (int e = 0; e < 4; ++e) o[e] = f2bf(fmaxf(acc[rr][e], 0.f));
        const int r  = g * 8 + rr;
        const int cc = (t >> 1) ^ (r & 7);   // chunk = (4t)/8 = t>>1
        *(u16x4*)(smem + r * 1024 + cc * 8 + (t & 1) * 4) = o;
      }
    }
    __syncthreads();
    // frag-store: wave wv writes k32 = wv, wv+4, ..., wv+28 (1KB coalesced)
#pragma unroll
    for (int i = 0; i < 8; ++i) {
      const int k32 = wv + i * 4;
      const int cc  = (k32 * 4 + kq) ^ (lrow & 7);
      u16x8 v = *(const u16x8*)(smem + lrow * 1024 + cc * 8);
      *(u16x8*)(h1f + (size_t)(k32 * 512 + mt) * 512 + l * 8) = v;
    }
  }
}

// ---------------------------------------------------------------------------
// Kernel 2: X2-GEMM direct-from-L2, no LDS, no drains.
// R5 post-mortem: concurrency x latency bound (18.8 B/cyc/CU << 64 L2 port;
// 11 TB/s << 34.5 aggregate); per-wave-pair frag fetch duplicated traffic.
// Fix: block = 64 rows x 256 cols (grid 128x4), 4 waves with the SAME A
// stream -> 3/4 of A reads become L1 hits; raw s_barrier every 8 k32 keeps
// the shared A window L1-resident (pacing only -- loads target registers,
// no memory ordering needed). B loads nontemporal (zero L1 reuse -> don't
// thrash A). K-major frag layout makes each iteration's frags one 4KB
// contiguous block. Wave tile 64x64, acc[4][4], 512 blocks = 2/CU,
// 8 waves/CU (same occupancy as R5). Per-output k32 chain still ascending
// 0..31 on identical bf16 fragments -> accumulators bit-exact; epilogue
// partition (16 disjoint 64-col groups) and addend multiset unchanged.
// ---------------------------------------------------------------------------
__global__ __launch_bounds__(256) void k_gemm(const u16* __restrict__ Af,
                                              const u16* __restrict__ Bf,
                                              const float* __restrict__ b21,
                                              const float* __restrict__ b22,
                                              const float* __restrict__ W31,
                                              const float* __restrict__ W32,
                                              float* __restrict__ head) {
  const int t = threadIdx.x, l = t & 63, wv = t >> 6;
  const int lrow = l & 15, kq = l >> 4;
  const int bx = blockIdx.x, by = blockIdx.y;
  // A frag (rt = bx*4 + i, k32) at (k32*512 + rt)*512 u16; wave-uniform.
  const u16* Ab = Af + (size_t)(bx * 4) * 512 + l * 8;
  // B frag (nt = by*16 + wv*4 + j, k32) at (k32*64 + nt)*512 u16.
  const u16* Bb = Bf + (size_t)(by * 16 + wv * 4) * 512 + l * 8;

  f32x4 acc[4][4];
#pragma unroll
  for (int i = 0; i < 4; ++i)
#pragma unroll
    for (int j = 0; j < 4; ++j) acc[i][j] = f32x4{0.f, 0.f, 0.f, 0.f};

  for (int kb = 0; kb < 4; ++kb) {
    if (kb) __builtin_amdgcn_s_barrier();   // pacing only: keeps the 4 waves'
                                            // shared A window inside L1
#pragma unroll 2
    for (int ki = 0; ki < 8; ++ki) {
      const int k32 = kb * 8 + ki;
      bf16x8 af[4], bfr[4];
#pragma unroll
      for (int i = 0; i < 4; ++i)
        af[i] = __builtin_bit_cast(bf16x8,
            *(const u16x8*)(Ab + (size_t)(k32 * 512 + i) * 512));
#pragma unroll
      for (int j = 0; j < 4; ++j)
        bfr[j] = __builtin_bit_cast(bf16x8,
            __builtin_nontemporal_load(
                (const u16x8*)(Bb + (size_t)(k32 * 64 + j) * 512)));
#pragma unroll
      for (int i = 0; i < 4; ++i)
#pragma unroll
        for (int j = 0; j < 4; ++j)
          acc[i][j] = __builtin_amdgcn_mfma_f32_16x16x32_bf16(af[i], bfr[j], acc[i][j], 0, 0, 0);
    }
  }

  // ---- fused head epilogue (verbatim math; col group = by*4+wv) ----
  // acc[i][j][rr]: row = bx*64 + i*16 + kq*4 + rr,
  //                col = by*256 + wv*64 + j*16 + lrow
  const int col0w = by * 256 + wv * 64;
  const bool isX21 = (col0w < 512);
  const float* Wh  = isX21 ? W31 : W32;      // [512][2] row-major
  const int   hoff = isX21 ? 0 : 2;

  float hx[16], hy[16];
#pragma unroll
  for (int n = 0; n < 16; ++n) { hx[n] = 0.f; hy[n] = 0.f; }
#pragma unroll
  for (int j = 0; j < 4; ++j) {
    int col  = col0w + j * 16 + lrow;
    int wcol = col & 511;
    f32x2 wvv = *(const f32x2*)(Wh + 2 * wcol);
    float bias = isX21 ? b21[col] : b22[wcol];
#pragma unroll
    for (int i = 0; i < 4; ++i)
#pragma unroll
      for (int rr = 0; rr < 4; ++rr) {
        float v = fmaxf(acc[i][j][rr] + bias, 0.f);
        hx[i * 4 + rr] = fmaf(v, wvv[0], hx[i * 4 + rr]);
        hy[i * 4 + rr] = fmaf(v, wvv[1], hy[i * 4 + rr]);
      }
  }
  // reduce across the 16 col-lanes (masks 1,2,4,8 stay inside the group)
#pragma unroll
  for (int m = 1; m <= 8; m <<= 1) {
#pragma unroll
    for (int n = 0; n < 16; ++n) {
      hx[n] += __shfl_xor(hx[n], m, 64);
      hy[n] += __shfl_xor(hy[n], m, 64);
    }
  }
  if (lrow == 0) {
#pragma unroll
    for (int i = 0; i < 4; ++i)
#pragma unroll
      for (int rr = 0; rr < 4; ++rr) {
        int row = bx * 64 + i * 16 + kq * 4 + rr;
        atomicAdd(head + 4 * (size_t)row + hoff,     hx[i * 4 + rr]);
        atomicAdd(head + 4 * (size_t)row + hoff + 1, hy[i * 4 + rr]);
      }
  }
}

// ---------------------------------------------------------------------------
// Kernel 3: rank-2 dual PGD QP. One thread per row; heads precomputed.
// Inner loop packed as f32x2 pairs (m, m+4) -> v_pk_{mul,add,fma,max}_f32.
// Sum trees and op order bit-identical to the scalar version (verified
// R1..R5: absmax unchanged at 0.015625).
// ---------------------------------------------------------------------------
__global__ __launch_bounds__(256) void k_qp(const float* __restrict__ x,
                                            const float* __restrict__ mean_,
                                            const float* __restrict__ std_,
                                            const float* __restrict__ head,
                                            const float* __restrict__ b31,
                                            const float* __restrict__ b32,
                                            const float* __restrict__ obstacles,
                                            float* __restrict__ out) {
  const int r = blockIdx.x * 256 + threadIdx.x;
  f32x4 hd = *(const f32x4*)(head + 4 * (size_t)r);
  float p0  = hd[0] + b31[0];
  float p1v = hd[1] + b31[1];
  float pp1 = 4.f / (1.f + expf(-(hd[2] + b32[0])));
  float pp2 = 4.f / (1.f + expf(-(hd[3] + b32[1])));

  const f32x4* xp = (const f32x4*)(x + (size_t)r * 8);
  f32x4 xa = xp[0], xb = xp[1];
  float px = xa[0] * std_[0] + mean_[0];
  float py = xa[1] * std_[1] + mean_[1];
  float th = xa[2] * std_[2] + mean_[2];
  float v  = xa[3] * std_[3] + mean_[3];
  float ax = xb[0] * std_[4] + mean_[4];
  float ay = xb[1] * std_[5] + mean_[5];
  float st = sinf(th), ct = cosf(th);
  float Lf2b = 2.f * v * v;

  float G0[9], G1[9], q[9];
  float s00 = 0.f, s01 = 0.f, s11 = 0.f;
#pragma unroll
  for (int m = 0; m < 9; ++m) {
    float ox, oy, orad;
    if (m < 8) {
      ox = obstacles[m * 3]; oy = obstacles[m * 3 + 1]; orad = obstacles[m * 3 + 2];
    } else { ox = ax; oy = ay; orad = 0.5f; }
    float R  = 0.6f + orad;                  // AGENT_RADIUS + orad + SAFETY
    float dx = px - ox, dy = py - oy;
    float bar  = dx * dx + dy * dy - R * R;
    float dct  = dx * ct + dy * st;
    float bdot = 2.f * v * dct;
    float g0 = 2.f * v * (dx * st - dy * ct);   // -LgLfbu1
    float g1 = -2.f * dct;                      // -LgLfbu2
    float h  = Lf2b + (pp1 + pp2) * bdot + pp1 * pp2 * bar;
    G0[m] = g0; G1[m] = g1;
    q[m] = g0 * p0 + g1 * p1v + h;
    s00 += g0 * g0; s01 += g0 * g1; s11 += g1 * g1;
  }
  float L = sqrtf(s00 * s00 + 2.f * s01 * s01 + s11 * s11) + 1e-6f;
  float alpha = 1.f / L;

  // pack pairs (m, m+4); m=8 stays scalar
  f32x2 G0p[4], G1p[4], qp2[4], lamp[4];
#pragma unroll
  for (int j = 0; j < 4; ++j) {
    G0p[j] = f32x2{G0[j], G0[j + 4]};
    G1p[j] = f32x2{G1[j], G1[j + 4]};
    qp2[j] = f32x2{q[j],  q[j + 4]};
    lamp[j] = f32x2{0.f, 0.f};
  }
  float G08 = G0[8], G18 = G1[8], q8 = q[8], lam8 = 0.f;
  const f32x2 nav = {-alpha, -alpha};
  const f32x2 z2  = {0.f, 0.f};

  for (int it = 0; it < 300; ++it) {
    f32x2 pv0[4], pv1[4];
#pragma unroll
    for (int j = 0; j < 4; ++j) {
      pv0[j] = G0p[j] * lamp[j];
      pv1[j] = G1p[j] * lamp[j];
    }
    float pr08 = G08 * lam8, pr18 = G18 * lam8;
    // c.x = (p0+p1)+(p2+p3), c.y = (p4+p5)+(p6+p7): same tree as scalar ver.
    f32x2 c0 = (pv0[0] + pv0[1]) + (pv0[2] + pv0[3]);
    f32x2 c1 = (pv1[0] + pv1[1]) + (pv1[2] + pv1[3]);
    float t0 = (c0.x + c0.y) + pr08;
    float t1 = (c1.x + c1.y) + pr18;
    f32x2 t0v = {t0, t0}, t1v = {t1, t1};
#pragma unroll
    for (int j = 0; j < 4; ++j) {
      f32x2 g = __builtin_elementwise_fma(G0p[j], t0v,
                __builtin_elementwise_fma(G1p[j], t1v, qp2[j]));
      lamp[j] = __builtin_elementwise_max(
                __builtin_elementwise_fma(nav, g, lamp[j]), z2);
    }
    float g8 = fmaf(G08, t0, fmaf(G18, t1, q8));
    lam8 = fmaxf(fmaf(-alpha, g8, lam8), 0.f);
  }

  float u0 = -p0, u1 = -p1v;
#pragma unroll
  for (int j = 0; j < 4; ++j) {            // m = 0..3
    u0 = fmaf(-G0p[j].x, lamp[j].x, u0);
    u1 = fmaf(-G1p[j].x, lamp[j].x, u1);
  }
#pragma unroll
  for (int j = 0; j < 4; ++j) {            // m = 4..7
    u0 = fmaf(-G0p[j].y, lamp[j].y, u0);
    u1 = fmaf(-G1p[j].y, lamp[j].y, u1);
  }
  u0 = fmaf(-G08, lam8, u0);               // m = 8
  u1 = fmaf(-G18, lam8, u1);
  *(f32x2*)(out + 2 * (size_t)r) = f32x2{u0, u1};
}

// ---------------------------------------------------------------------------
extern "C" void kernel_launch(void* const* d_in, const int* in_sizes, int n_in,
                              void* d_out, int out_size, void* d_ws, size_t ws_size,
                              hipStream_t stream) {
  const float* x    = (const float*)d_in[0];
  const float* mean_= (const float*)d_in[1];
  const float* std_ = (const float*)d_in[2];
  const float* W1   = (const float*)d_in[3];
  const float* b1   = (const float*)d_in[4];
  const float* W21  = (const float*)d_in[5];
  const float* b21  = (const float*)d_in[6];
  const float* W22  = (const float*)d_in[7];
  const float* b22  = (const float*)d_in[8];
  // d_in[9],[10] = W23,b23 : dead code in reference (x33 unused)
  const float* W31  = (const float*)d_in[11];
  const float* b31  = (const float*)d_in[12];
  const float* W32  = (const float*)d_in[13];
  const float* b32  = (const float*)d_in[14];
  // d_in[15],[16] = W33,b33 : dead code
  const float* obst = (const float*)d_in[17];
  float* out = (float*)d_out;

  char* ws = (char*)d_ws;
  u16*   Wtf  = (u16*)ws;                                   // 2 MB frag layout
  u16*   h1f  = (u16*)(ws + (size_t)(1 << 21));             // 16 MB frag layout
  float* head = (float*)(ws + (size_t)(1 << 21) + (size_t)(1 << 24)); // 128 KB

  k_prep<<<256 + 512, 256, 0, stream>>>(W21, W22, Wtf, x, W1, b1, h1f, head);
  k_gemm<<<dim3(128, 4), 256, 0, stream>>>(h1f, Wtf, b21, b22, W31, W32, head);
  k_qp  <<<32, 256, 0, stream>>>(x, mean_, std_, head, b31, b32, obst, out);
}

// Round 7
// 159.142 us; speedup vs baseline: 1.1199x; 1.1199x over previous
//
#include <hip/hip_runtime.h>
#include <cstdint>
#include <cstddef>

typedef unsigned short u16;
typedef u16   u16x8  __attribute__((ext_vector_type(8)));
typedef u16   u16x4  __attribute__((ext_vector_type(4)));
typedef __bf16 bf16x8 __attribute__((ext_vector_type(8)));
typedef float f32x4  __attribute__((ext_vector_type(4)));
typedef float f32x2  __attribute__((ext_vector_type(2)));

__device__ __forceinline__ u16 f2bf(float f) {
  unsigned int x = __builtin_bit_cast(unsigned int, f);
  x += 0x7fffu + ((x >> 16) & 1u);   // RNE
  return (u16)(x >> 16);
}

// async global->LDS, 16B per lane. LDS dest must be wave-uniform base + lane*16.
__device__ __forceinline__ void gld_lds16(const u16* g, u16* l) {
  __builtin_amdgcn_global_load_lds(
      (const __attribute__((address_space(1))) unsigned int*)g,
      (__attribute__((address_space(3))) unsigned int*)l, 16, 0, 0);
}

// ---------------------------------------------------------------------------
// Kernel 1 (fat): blocks 0..255  -> transpose W21/W22 f32 -> bf16 Wt [n][k]
//                 blocks 256..767-> h1 = relu(x @ W1 + b1), 16 rows per block
//                                   (halves W1 L2 traffic vs 8 rows/block);
//                                   zero head rows (ws poisoned).
// Both bodies verified (R2/R3 runs, absmax 0.015625). Row-major outputs.
// ---------------------------------------------------------------------------
__global__ __launch_bounds__(256) void k_prep(const float* __restrict__ W21,
                                              const float* __restrict__ W22,
                                              u16* __restrict__ Wt,
                                              const float* __restrict__ x,
                                              const float* __restrict__ W1,
                                              const float* __restrict__ b1,
                                              u16* __restrict__ h1,
                                              float* __restrict__ head) {
  __shared__ u16 s[64][65];
  const int b = blockIdx.x;
  if (b < 256) {
    const int mat = b >> 7;
    const int tt  = b & 127;
    const int k0  = (tt >> 3) * 64;
    const int n0  = (tt & 7) * 64;
    const float* W = mat ? W22 : W21;
    const int tx = threadIdx.x & 63;
    const int ty = threadIdx.x >> 6;
#pragma unroll
    for (int i = 0; i < 16; ++i) {
      int r = i * 4 + ty;
      s[r][tx] = f2bf(W[(size_t)(k0 + r) * 512 + n0 + tx]);
    }
    __syncthreads();
    const int nbase = mat * 512 + n0;
#pragma unroll
    for (int i = 0; i < 16; ++i) {
      int r = i * 4 + ty;
      Wt[(size_t)(nbase + r) * 1024 + k0 + tx] = s[tx][r];
    }
  } else {
    const int row0t = (b - 256) * 16;
    if (threadIdx.x < 16)
      *(f32x4*)(head + 4 * (size_t)(row0t + threadIdx.x)) = f32x4{0.f, 0.f, 0.f, 0.f};
    const int c4 = threadIdx.x * 4;
    f32x4 bv = *(const f32x4*)(b1 + c4);
    for (int g = 0; g < 2; ++g) {
      const int row0 = row0t + g * 8;
      f32x4 acc[8];
#pragma unroll
      for (int r = 0; r < 8; ++r) acc[r] = bv;
#pragma unroll
      for (int f = 0; f < 8; ++f) {
        f32x4 wv = *(const f32x4*)(W1 + f * 1024 + c4);
#pragma unroll
        for (int r = 0; r < 8; ++r) {
          float xv = x[(size_t)(row0 + r) * 8 + f];   // block-uniform -> s_load
#pragma unroll
          for (int e = 0; e < 4; ++e) acc[r][e] = fmaf(xv, wv[e], acc[r][e]);
        }
      }
#pragma unroll
      for (int r = 0; r < 8; ++r) {
        u16x4 o;
#pragma unroll
        for (int e = 0; e < 4; ++e) o[e] = f2bf(fmaxf(acc[r][e], 0.f));
        *(u16x4*)(h1 + (size_t)(row0 + r) * 1024 + c4) = o;
      }
    }
  }
}

// ---------------------------------------------------------------------------
// Kernel 2: X2-GEMM (mfma 16x16x32, 128x128 tile, BK=64) + fused head
// epilogue. EXACT R2 kernel (the 160.5us run) -- best of 5 measured GEMM
// structures (~41 / 53.7 / 48.8 / 46.5 / 54.6 us). LDS dbuf 64KB, one
// barrier per K-iter, global_load_lds DMA, XOR chunk swizzle (0 conflicts).
// Six-round model: delivery is capped at ~19 B/cyc/CU composite L2/L3
// (per-XCD working set A+B = 4MB = L2 capacity); 2 blk/CU dbuf is the best
// operating point, grid-capped at 512 blocks for this M,N.
// ---------------------------------------------------------------------------
__global__ __launch_bounds__(256) void k_gemm(const u16* __restrict__ A,
                                              const u16* __restrict__ Bt,
                                              const float* __restrict__ b21,
                                              const float* __restrict__ b22,
                                              const float* __restrict__ W31,
                                              const float* __restrict__ W32,
                                              float* __restrict__ head) {
  constexpr int K  = 1024;
  constexpr int BK = 64;
  constexpr int NT = K / BK;           // 16 K-tiles
  __shared__ u16 As[2][128 * 64];      // 16 KB each
  __shared__ u16 Bs[2][128 * 64];      // total 64 KB (static limit; 2 blk/CU)

  const int t    = threadIdx.x;
  const int row0 = blockIdx.x * 128;   // 64 M-tiles
  const int col0 = blockIdx.y * 128;   // 8 N-tiles
  const int w    = t >> 6;
  const int lane = t & 63;
  const int wr   = w >> 1, wc = w & 1; // 2x2 wave grid, 64x64 per wave
  const int lrow = lane & 15;
  const int kq   = lane >> 4;          // frag k-chunk within a k32 step

  // staging slots m=0..3: s = t + 256m; row = s>>3, stored chunk = s&7,
  // fetched global kchunk = (s&7) ^ ((s>>3)&7)
  const u16* gA[4];
  const u16* gB[4];
  int lo[4];
#pragma unroll
  for (int m = 0; m < 4; ++m) {
    const int s  = t + 256 * m;
    const int gc = (s & 7) ^ ((s >> 3) & 7);
    gA[m] = A  + (size_t)(row0 + (s >> 3)) * K + gc * 8;
    gB[m] = Bt + (size_t)(col0 + (s >> 3)) * K + gc * 8;
    lo[m] = s * 8;
  }
  // read-side physical chunk offsets for k32-steps 0/1 (logical chunk
  // s32*4+kq at row r -> stored chunk (s32*4+kq)^(r&7); r&7 == lrow&7)
  const int po0 = (((0 * 4) + kq) ^ (lrow & 7)) * 8;
  const int po1 = (((1 * 4) + kq) ^ (lrow & 7)) * 8;

  f32x4 acc[4][4];
#pragma unroll
  for (int i = 0; i < 4; ++i)
#pragma unroll
    for (int j = 0; j < 4; ++j) acc[i][j] = f32x4{0.f, 0.f, 0.f, 0.f};

  // prologue: DMA tile 0 into buffer 0
#pragma unroll
  for (int m = 0; m < 4; ++m) {
    gld_lds16(gA[m], As[0] + lo[m]);
    gld_lds16(gB[m], Bs[0] + lo[m]);
  }

  for (int kt = 0; kt < NT; ++kt) {
    const int cur = kt & 1, nxt = cur ^ 1;
    __syncthreads();                   // drains DMA into buf[cur]; orders WAR

    if (kt + 1 < NT) {                 // DMA next tile into buf[nxt]
      const int ko = (kt + 1) * BK;
#pragma unroll
      for (int m = 0; m < 4; ++m) {
        gld_lds16(gA[m] + ko, As[nxt] + lo[m]);
        gld_lds16(gB[m] + ko, Bs[nxt] + lo[m]);
      }
    }

#pragma unroll
    for (int s32 = 0; s32 < 2; ++s32) {
      const int po = s32 ? po1 : po0;
      bf16x8 af[4], bfr[4];
#pragma unroll
      for (int i = 0; i < 4; ++i)
        af[i] = __builtin_bit_cast(bf16x8,
            *(const u16x8*)(As[cur] + (wr * 64 + i * 16 + lrow) * 64 + po));
#pragma unroll
      for (int j = 0; j < 4; ++j)
        bfr[j] = __builtin_bit_cast(bf16x8,
            *(const u16x8*)(Bs[cur] + (wc * 64 + j * 16 + lrow) * 64 + po));
#pragma unroll
      for (int i = 0; i < 4; ++i)
#pragma unroll
        for (int j = 0; j < 4; ++j)
          acc[i][j] = __builtin_amdgcn_mfma_f32_16x16x32_bf16(af[i], bfr[j], acc[i][j], 0, 0, 0);
    }
  }

  // ---- fused head epilogue ----
  // acc[i][j][rr]: row = row0+wr*64+i*16+kq*4+rr, col = col0+wc*64+j*16+lrow
  const bool isX21 = (col0 < 512);
  const float* Wh  = isX21 ? W31 : W32;      // [512][2] row-major
  const int   hoff = isX21 ? 0 : 2;

  float hx[16], hy[16];
#pragma unroll
  for (int n = 0; n < 16; ++n) { hx[n] = 0.f; hy[n] = 0.f; }
#pragma unroll
  for (int j = 0; j < 4; ++j) {
    int col  = col0 + wc * 64 + j * 16 + lrow;
    int wcol = col & 511;
    f32x2 wv = *(const f32x2*)(Wh + 2 * wcol);
    float bias = isX21 ? b21[col] : b22[wcol];
#pragma unroll
    for (int i = 0; i < 4; ++i)
#pragma unroll
      for (int rr = 0; rr < 4; ++rr) {
        float v = fmaxf(acc[i][j][rr] + bias, 0.f);
        hx[i * 4 + rr] = fmaf(v, wv[0], hx[i * 4 + rr]);
        hy[i * 4 + rr] = fmaf(v, wv[1], hy[i * 4 + rr]);
      }
  }
  // reduce across the 16 col-lanes (masks 1,2,4,8 stay inside the group)
#pragma unroll
  for (int m = 1; m <= 8; m <<= 1) {
#pragma unroll
    for (int n = 0; n < 16; ++n) {
      hx[n] += __shfl_xor(hx[n], m, 64);
      hy[n] += __shfl_xor(hy[n], m, 64);
    }
  }
  if (lrow == 0) {
#pragma unroll
    for (int i = 0; i < 4; ++i)
#pragma unroll
      for (int rr = 0; rr < 4; ++rr) {
        int row = row0 + wr * 64 + i * 16 + kq * 4 + rr;
        atomicAdd(head + 4 * (size_t)row + hoff,     hx[i * 4 + rr]);
        atomicAdd(head + 4 * (size_t)row + hoff + 1, hy[i * 4 + rr]);
      }
  }
}

// ---------------------------------------------------------------------------
// Kernel 3: rank-2 dual PGD QP. One thread per row; heads precomputed.
// Inner loop packed as f32x2 pairs (m, m+4) -> v_pk_{mul,add,fma,max}_f32.
// Sum trees and op order bit-identical to the scalar version (verified
// R1..R6: absmax unchanged at 0.015625).
// ---------------------------------------------------------------------------
__global__ __launch_bounds__(256) void k_qp(const float* __restrict__ x,
                                            const float* __restrict__ mean_,
                                            const float* __restrict__ std_,
                                            const float* __restrict__ head,
                                            const float* __restrict__ b31,
                                            const float* __restrict__ b32,
                                            const float* __restrict__ obstacles,
                                            float* __restrict__ out) {
  const int r = blockIdx.x * 256 + threadIdx.x;
  f32x4 hd = *(const f32x4*)(head + 4 * (size_t)r);
  float p0  = hd[0] + b31[0];
  float p1v = hd[1] + b31[1];
  float pp1 = 4.f / (1.f + expf(-(hd[2] + b32[0])));
  float pp2 = 4.f / (1.f + expf(-(hd[3] + b32[1])));

  const f32x4* xp = (const f32x4*)(x + (size_t)r * 8);
  f32x4 xa = xp[0], xb = xp[1];
  float px = xa[0] * std_[0] + mean_[0];
  float py = xa[1] * std_[1] + mean_[1];
  float th = xa[2] * std_[2] + mean_[2];
  float v  = xa[3] * std_[3] + mean_[3];
  float ax = xb[0] * std_[4] + mean_[4];
  float ay = xb[1] * std_[5] + mean_[5];
  float st = sinf(th), ct = cosf(th);
  float Lf2b = 2.f * v * v;

  float G0[9], G1[9], q[9];
  float s00 = 0.f, s01 = 0.f, s11 = 0.f;
#pragma unroll
  for (int m = 0; m < 9; ++m) {
    float ox, oy, orad;
    if (m < 8) {
      ox = obstacles[m * 3]; oy = obstacles[m * 3 + 1]; orad = obstacles[m * 3 + 2];
    } else { ox = ax; oy = ay; orad = 0.5f; }
    float R  = 0.6f + orad;                  // AGENT_RADIUS + orad + SAFETY
    float dx = px - ox, dy = py - oy;
    float bar  = dx * dx + dy * dy - R * R;
    float dct  = dx * ct + dy * st;
    float bdot = 2.f * v * dct;
    float g0 = 2.f * v * (dx * st - dy * ct);   // -LgLfbu1
    float g1 = -2.f * dct;                      // -LgLfbu2
    float h  = Lf2b + (pp1 + pp2) * bdot + pp1 * pp2 * bar;
    G0[m] = g0; G1[m] = g1;
    q[m] = g0 * p0 + g1 * p1v + h;
    s00 += g0 * g0; s01 += g0 * g1; s11 += g1 * g1;
  }
  float L = sqrtf(s00 * s00 + 2.f * s01 * s01 + s11 * s11) + 1e-6f;
  float alpha = 1.f / L;

  // pack pairs (m, m+4); m=8 stays scalar
  f32x2 G0p[4], G1p[4], qp2[4], lamp[4];
#pragma unroll
  for (int j = 0; j < 4; ++j) {
    G0p[j] = f32x2{G0[j], G0[j + 4]};
    G1p[j] = f32x2{G1[j], G1[j + 4]};
    qp2[j] = f32x2{q[j],  q[j + 4]};
    lamp[j] = f32x2{0.f, 0.f};
  }
  float G08 = G0[8], G18 = G1[8], q8 = q[8], lam8 = 0.f;
  const f32x2 nav = {-alpha, -alpha};
  const f32x2 z2  = {0.f, 0.f};

  for (int it = 0; it < 300; ++it) {
    f32x2 pv0[4], pv1[4];
#pragma unroll
    for (int j = 0; j < 4; ++j) {
      pv0[j] = G0p[j] * lamp[j];
      pv1[j] = G1p[j] * lamp[j];
    }
    float pr08 = G08 * lam8, pr18 = G18 * lam8;
    // c.x = (p0+p1)+(p2+p3), c.y = (p4+p5)+(p6+p7): same tree as scalar ver.
    f32x2 c0 = (pv0[0] + pv0[1]) + (pv0[2] + pv0[3]);
    f32x2 c1 = (pv1[0] + pv1[1]) + (pv1[2] + pv1[3]);
    float t0 = (c0.x + c0.y) + pr08;
    float t1 = (c1.x + c1.y) + pr18;
    f32x2 t0v = {t0, t0}, t1v = {t1, t1};
#pragma unroll
    for (int j = 0; j < 4; ++j) {
      f32x2 g = __builtin_elementwise_fma(G0p[j], t0v,
                __builtin_elementwise_fma(G1p[j], t1v, qp2[j]));
      lamp[j] = __builtin_elementwise_max(
                __builtin_elementwise_fma(nav, g, lamp[j]), z2);
    }
    float g8 = fmaf(G08, t0, fmaf(G18, t1, q8));
    lam8 = fmaxf(fmaf(-alpha, g8, lam8), 0.f);
  }

  float u0 = -p0, u1 = -p1v;
#pragma unroll
  for (int j = 0; j < 4; ++j) {            // m = 0..3
    u0 = fmaf(-G0p[j].x, lamp[j].x, u0);
    u1 = fmaf(-G1p[j].x, lamp[j].x, u1);
  }
#pragma unroll
  for (int j = 0; j < 4; ++j) {            // m = 4..7
    u0 = fmaf(-G0p[j].y, lamp[j].y, u0);
    u1 = fmaf(-G1p[j].y, lamp[j].y, u1);
  }
  u0 = fmaf(-G08, lam8, u0);               // m = 8
  u1 = fmaf(-G18, lam8, u1);
  *(f32x2*)(out + 2 * (size_t)r) = f32x2{u0, u1};
}

// ---------------------------------------------------------------------------
extern "C" void kernel_launch(void* const* d_in, const int* in_sizes, int n_in,
                              void* d_out, int out_size, void* d_ws, size_t ws_size,
                              hipStream_t stream) {
  const float* x    = (const float*)d_in[0];
  const float* mean_= (const float*)d_in[1];
  const float* std_ = (const float*)d_in[2];
  const float* W1   = (const float*)d_in[3];
  const float* b1   = (const float*)d_in[4];
  const float* W21  = (const float*)d_in[5];
  const float* b21  = (const float*)d_in[6];
  const float* W22  = (const float*)d_in[7];
  const float* b22  = (const float*)d_in[8];
  // d_in[9],[10] = W23,b23 : dead code in reference (x33 unused)
  const float* W31  = (const float*)d_in[11];
  const float* b31  = (const float*)d_in[12];
  const float* W32  = (const float*)d_in[13];
  const float* b32  = (const float*)d_in[14];
  // d_in[15],[16] = W33,b33 : dead code
  const float* obst = (const float*)d_in[17];
  float* out = (float*)d_out;

  char* ws = (char*)d_ws;
  u16*   Wt   = (u16*)ws;                                   // 2 MB
  u16*   h1   = (u16*)(ws + (size_t)(1 << 21));             // 16 MB
  float* head = (float*)(ws + (size_t)(1 << 21) + (size_t)(1 << 24)); // 128 KB

  k_prep<<<256 + 512, 256, 0, stream>>>(W21, W22, Wt, x, W1, b1, h1, head);
  k_gemm<<<dim3(64, 8), 256, 0, stream>>>(h1, Wt, b21, b22, W31, W32, head);
  k_qp  <<<32, 256, 0, stream>>>(x, mean_, std_, head, b31, b32, obst, out);
}